// Round 18
// baseline (6552.760 us; speedup 1.0000x reference)
//
#include <hip/hip_runtime.h>
#include <hip/hip_bf16.h>
#include <math.h>

#define BB 8
#define NN 8192
#define SS 2048
#define NSAMP 32

typedef unsigned long long u64;

// K0: transpose xyz (B,3,N) f32 -> X (B,N,3) f32
__global__ void k_transpose(const float* __restrict__ xyz, float* __restrict__ X) {
    int e = blockIdx.x * 256 + threadIdx.x;
    if (e >= BB * 3 * NN) return;
    int n = e % NN;
    int bc = e / NN;
    int c = bc % 3;
    int b = bc / 3;
    X[((size_t)(b * NN + n)) * 3 + c] = xyz[e];
}

// K1: farthest point sampling, one block per batch. DIRECT distance form,
// ascending, separately rounded (NO FMA) — np.sum((x-c)**2,-1) semantics.
// VERIFIED: output 0 passed rounds 2-15,17; expanded form falsified (r16).
// DO NOT TOUCH.
__global__ __launch_bounds__(1024) void k_fps(const float* __restrict__ X,
                                              float* __restrict__ NXYZ) {
    __shared__ float wv_[16];
    __shared__ int wn_[16];
    int b = blockIdx.x;
    int tid = threadIdx.x;
    const float* xb = X + (size_t)b * NN * 3;
    float px[8], py[8], pz[8], dist[8];
#pragma unroll
    for (int i = 0; i < 8; ++i) {
        int n = tid + (i << 10);
        px[i] = xb[(size_t)n * 3 + 0];
        py[i] = xb[(size_t)n * 3 + 1];
        pz[i] = xb[(size_t)n * 3 + 2];
        dist[i] = 1e10f;
    }
    float c0 = xb[0], c1 = xb[1], c2 = xb[2];
    int lane = tid & 63, wv = tid >> 6;
    for (int t = 0; t < SS; ++t) {
        if (tid == 0) {
            float* o = NXYZ + ((size_t)b * SS + t) * 3;
            o[0] = c0; o[1] = c1; o[2] = c2;
        }
        float bestv = -1.0f; int bestn = 0;
#pragma unroll
        for (int i = 0; i < 8; ++i) {
            float dx = __fsub_rn(px[i], c0);
            float dy = __fsub_rn(py[i], c1);
            float dz = __fsub_rn(pz[i], c2);
            float dd = __fadd_rn(__fadd_rn(__fmul_rn(dx, dx), __fmul_rn(dy, dy)),
                                 __fmul_rn(dz, dz));
            float nd = fminf(dist[i], dd);
            dist[i] = nd;
            if (nd > bestv) { bestv = nd; bestn = tid + (i << 10); }
        }
        // wave-level reduction: max value, ties -> smallest index
#pragma unroll
        for (int off = 32; off > 0; off >>= 1) {
            float ov = __shfl_down(bestv, (unsigned)off, 64);
            int on = __shfl_down(bestn, (unsigned)off, 64);
            if (ov > bestv || (ov == bestv && on < bestn)) { bestv = ov; bestn = on; }
        }
        if (lane == 0) { wv_[wv] = bestv; wn_[wv] = bestn; }
        __syncthreads();
        float kv = wv_[0]; int kn = wn_[0];
#pragma unroll
        for (int i = 1; i < 16; ++i) {
            float ov = wv_[i]; int on = wn_[i];
            if (ov > kv || (ov == kv && on < kn)) { kv = ov; kn = on; }
        }
        int cur = kn;
        c0 = xb[(size_t)cur * 3 + 0];
        c1 = xb[(size_t)cur * 3 + 1];
        c2 = xb[(size_t)cur * 3 + 2];
        __syncthreads();  // protect wv_/wn_ before next iteration's writes
    }
}

// K2: ball query. One wave per center. O2' outer — the classic += port with
// the dst-sum added BEFORE the src-sum:
//   dist  = -2 * matmul(src, dstT)     -> BLAS k=3 asc-FMA:
//           dot = fma(c2,x2, fma(c1,x1, fl(c0*x0)))
//   dist += np.sum(dst**2,-1)[:,None,:] -> t   = fl(-2*dot + B)  (B asc noFMA)
//   dist += np.sum(src**2,-1)[:,:,None] -> sqr = fl(t + A)       (A asc noFMA)
// exclude sqr > 0.04f.
// O2' is the unique untried member of the complete left-to-right outer space
// {O1 fl(A+B)-2E, O2 fl(-2E+A)+B, O2' fl(-2E+B)+A}; an outer-rounding
// difference is the only mechanism large enough (up to 16 sqr-ulps) to explain
// the residual flip surviving r12's +1-ulp threshold shift.
__global__ __launch_bounds__(256) void k_ballq(const float* __restrict__ X,
                                               const float* __restrict__ NXYZ,
                                               int* __restrict__ GI) {
    int wv = threadIdx.x >> 6, lane = threadIdx.x & 63;
    int gs = blockIdx.x * 4 + wv;           // 0..16383
    int b = gs >> 11;
    const float* xb = X + (size_t)b * NN * 3;
    float c0 = NXYZ[(size_t)gs * 3 + 0];
    float c1 = NXYZ[(size_t)gs * 3 + 1];
    float c2 = NXYZ[(size_t)gs * 3 + 2];
    float A = __fadd_rn(__fadd_rn(__fmul_rn(c0, c0), __fmul_rn(c1, c1)),
                        __fmul_rn(c2, c2));
    const float R2 = 0.04f;
    int cnt = 0, first = 0;
    int* gout = GI + ((size_t)gs << 5);
    for (int r = 0; r < 128 && cnt < 32; ++r) {
        int n = (r << 6) + lane;
        float x0 = xb[(size_t)n * 3 + 0];
        float x1 = xb[(size_t)n * 3 + 1];
        float x2 = xb[(size_t)n * 3 + 2];
        float Bx = __fadd_rn(__fadd_rn(__fmul_rn(x0, x0), __fmul_rn(x1, x1)),
                             __fmul_rn(x2, x2));
        float dot = fmaf(c2, x2, fmaf(c1, x1, __fmul_rn(c0, x0)));  // BLAS asc-FMA
        float t = __fadd_rn(__fmul_rn(-2.0f, dot), Bx);             // += B first
        float sqr = __fadd_rn(t, A);                                // += A second
        bool pred = !(sqr > R2);
        u64 mask = __ballot(pred);
        int rank = cnt + __popcll(mask & ((1ull << lane) - 1ull));
        if (pred && rank < 32) gout[rank] = n;
        if (cnt == 0 && mask) first = (r << 6) + (__ffsll((long long)mask) - 1);
        cnt += __popcll(mask);
    }
    if (cnt < 32 && lane >= cnt && lane < 32) gout[lane] = first;
}

// K3: build group features in LDS + attention block 1 + maxpool. One block per
// (b,s) group: 32 tokens x 64 dims.
__global__ __launch_bounds__(256) void k_attn1(
    const float* __restrict__ X, const float* __restrict__ NXYZ,
    const int* __restrict__ GI, const float* __restrict__ P,
    const float* __restrict__ wq, const float* __restrict__ wk,
    const float* __restrict__ wv, const float* __restrict__ wo,
    const float* __restrict__ wp, const float* __restrict__ bp,
    float* __restrict__ FMID) {
    __shared__ float feat[32][65], qS[32][65], kS[32][65], vS[32][65];
    __shared__ float sc[32][33];
    __shared__ float pos[32][3];
    __shared__ int giS[32];
    __shared__ float ctr[3];
    int gs = blockIdx.x;
    int b = gs >> 11;
    int tid = threadIdx.x;
    if (tid < 32) giS[tid] = GI[((size_t)gs << 5) + tid];
    if (tid < 3) ctr[tid] = NXYZ[(size_t)gs * 3 + tid];
    __syncthreads();
    const float* xb = X + (size_t)b * NN * 3;
    const float* pb = P + (size_t)b * 61 * NN;
    int d = tid & 63, g4 = tid >> 6;
    for (int jj = 0; jj < 8; ++jj) {
        int j = g4 * 8 + jj;
        int idx = giS[j];
        float val;
        if (d < 3) {
            float xv = xb[(size_t)idx * 3 + d];
            pos[j][d] = xv;
            val = __fsub_rn(xv, ctr[d]);
        } else {
            val = pb[(size_t)(d - 3) * NN + idx];
        }
        feat[j][d] = val;
    }
    __syncthreads();
    float aq[8], ak[8], av[8];
#pragma unroll
    for (int i = 0; i < 8; ++i) { aq[i] = 0.f; ak[i] = 0.f; av[i] = 0.f; }
    for (int kk = 0; kk < 64; ++kk) {
        float wqv = wq[kk * 64 + d];
        float wkv = wk[kk * 64 + d];
        float wvv = wv[kk * 64 + d];
#pragma unroll
        for (int i = 0; i < 8; ++i) {
            float f = feat[g4 + 4 * i][kk];
            aq[i] = fmaf(f, wqv, aq[i]);
            ak[i] = fmaf(f, wkv, ak[i]);
            av[i] = fmaf(f, wvv, av[i]);
        }
    }
    {
        float wp0 = wp[d], wp1 = wp[64 + d], wp2 = wp[128 + d];
        float bpd = bp[d];
#pragma unroll
        for (int i = 0; i < 8; ++i) {
            int j = g4 + 4 * i;
            float pterm = fmaf(pos[j][2], wp2, fmaf(pos[j][1], wp1, pos[j][0] * wp0)) + bpd;
            av[i] += pterm;
            qS[j][d] = aq[i]; kS[j][d] = ak[i]; vS[j][d] = av[i];
        }
    }
    __syncthreads();
    for (int e = tid; e < 1024; e += 256) {
        int r = e >> 5, ci = e & 31;
        float acc = 0.f;
        for (int kk = 0; kk < 64; ++kk) acc = fmaf(qS[r][kk], kS[ci][kk], acc);
        sc[r][ci] = acc * 0.125f;
    }
    __syncthreads();
    if (tid < 32) {
        float m = -INFINITY;
        for (int i2 = 0; i2 < 32; ++i2) m = fmaxf(m, sc[tid][i2]);
        float sum = 0.f;
        for (int i2 = 0; i2 < 32; ++i2) {
            float e2 = expf(sc[tid][i2] - m);
            sc[tid][i2] = e2; sum += e2;
        }
        float inv = 1.0f / sum;
        for (int i2 = 0; i2 < 32; ++i2) sc[tid][i2] *= inv;
    }
    __syncthreads();
    // a @ v -> reuse qS as attention output
    for (int e = tid; e < 2048; e += 256) {
        int j = e >> 6, dd2 = e & 63;
        float acc = 0.f;
        for (int s2 = 0; s2 < 32; ++s2) acc = fmaf(sc[j][s2], vS[s2][dd2], acc);
        qS[j][dd2] = acc;
    }
    __syncthreads();
    float o[8];
#pragma unroll
    for (int i = 0; i < 8; ++i) o[i] = feat[g4 + 4 * i][d];
    for (int kk = 0; kk < 64; ++kk) {
        float wov = wo[kk * 64 + d];
#pragma unroll
        for (int i = 0; i < 8; ++i) o[i] = fmaf(qS[g4 + 4 * i][kk], wov, o[i]);
    }
    float pm = o[0];
#pragma unroll
    for (int i = 1; i < 8; ++i) pm = fmaxf(pm, o[i]);
    __syncthreads();
    feat[g4][d] = pm;
    __syncthreads();
    if (tid < 64) {
        float mm = fmaxf(fmaxf(feat[0][tid], feat[1][tid]),
                         fmaxf(feat[2][tid], feat[3][tid]));
        FMID[((size_t)gs << 6) + tid] = mm;
    }
}

// K4: q/k/v projections for attention block 2 (rows = B*2048)
__global__ __launch_bounds__(256) void k_qkv2(
    const float* __restrict__ FMID, const float* __restrict__ NXYZ,
    const float* __restrict__ wq, const float* __restrict__ wk,
    const float* __restrict__ wv, const float* __restrict__ wp,
    const float* __restrict__ bpv,
    float* __restrict__ Q2, float* __restrict__ K2, float* __restrict__ V2) {
    __shared__ float f[4][65];
    int tid = threadIdx.x;
    int lr = tid >> 6, d = tid & 63;
    size_t row = (size_t)blockIdx.x * 4 + lr;
    f[lr][d] = FMID[row * 64 + d];
    __syncthreads();
    float aq = 0.f, ak = 0.f, av = 0.f;
    for (int kk = 0; kk < 64; ++kk) {
        float fv = f[lr][kk];
        aq = fmaf(fv, wq[kk * 64 + d], aq);
        ak = fmaf(fv, wk[kk * 64 + d], ak);
        av = fmaf(fv, wv[kk * 64 + d], av);
    }
    float p0 = NXYZ[row * 3], p1 = NXYZ[row * 3 + 1], p2 = NXYZ[row * 3 + 2];
    av += fmaf(p2, wp[128 + d], fmaf(p1, wp[64 + d], p0 * wp[d])) + bpv[d];
    Q2[row * 64 + d] = aq; K2[row * 64 + d] = ak; V2[row * 64 + d] = av;
}

// K5: attention block 2, flash-style online softmax. 16 Q-rows per block
// (4 waves x 4 rows), K/V staged in padded LDS tiles of 64 rows.
__global__ __launch_bounds__(256) void k_attn2(
    const float* __restrict__ Q2, const float* __restrict__ K2,
    const float* __restrict__ V2, const float* __restrict__ FMID,
    const float* __restrict__ wo, float* __restrict__ out1) {
    __shared__ float kT[64][65], vT[64][65], qSh[16][65];
    int tid = threadIdx.x;
    int wv = tid >> 6, lane = tid & 63;
    int b = blockIdx.x >> 7, rb = blockIdx.x & 127;
    size_t rbase = (size_t)b * SS + rb * 16;
    for (int e = tid; e < 16 * 64; e += 256) {
        int r = e >> 6, dd = e & 63;
        qSh[r][dd] = Q2[(rbase + r) * 64 + dd];
    }
    float acc[4] = {0.f, 0.f, 0.f, 0.f};
    float mr[4] = {-INFINITY, -INFINITY, -INFINITY, -INFINITY};
    float lr[4] = {0.f, 0.f, 0.f, 0.f};
    for (int tt = 0; tt < 32; ++tt) {
        __syncthreads();
        for (int e = tid; e < 4096; e += 256) {
            int r = e >> 6, dd = e & 63;
            size_t src = ((size_t)b * SS + tt * 64 + r) * 64 + dd;
            kT[r][dd] = K2[src];
            vT[r][dd] = V2[src];
        }
        __syncthreads();
#pragma unroll
        for (int rr = 0; rr < 4; ++rr) {
            int lrow = wv * 4 + rr;
            float sj = 0.f;
            for (int dd = 0; dd < 64; ++dd) sj = fmaf(qSh[lrow][dd], kT[lane][dd], sj);
            sj *= 0.125f;
            float tm = sj;
#pragma unroll
            for (int off = 32; off > 0; off >>= 1)
                tm = fmaxf(tm, __shfl_down(tm, (unsigned)off, 64));
            tm = __shfl(tm, 0, 64);
            float mnew = fmaxf(mr[rr], tm);
            float alpha = expf(mr[rr] - mnew);
            float pj = expf(sj - mnew);
            float ps = pj;
#pragma unroll
            for (int off = 32; off > 0; off >>= 1) ps += __shfl_down(ps, (unsigned)off, 64);
            ps = __shfl(ps, 0, 64);
            lr[rr] = lr[rr] * alpha + ps;
            float a2 = acc[rr] * alpha;
            for (int j = 0; j < 64; ++j) {
                float pb2 = __shfl(pj, j, 64);
                a2 = fmaf(pb2, vT[j][lane], a2);
            }
            acc[rr] = a2;
            mr[rr] = mnew;
        }
    }
#pragma unroll
    for (int rr = 0; rr < 4; ++rr) {
        int lrow = wv * 4 + rr;
        size_t row = rbase + lrow;
        float avl = acc[rr] / lr[rr];
        float o = FMID[row * 64 + lane];
        for (int kk = 0; kk < 64; ++kk) {
            float avk = __shfl(avl, kk, 64);
            o = fmaf(avk, wo[kk * 64 + lane], o);
        }
        out1[((size_t)b * 64 + lane) * SS + (size_t)(rb * 16 + lrow)] = o;
    }
}

// K6: new_xyz (B,S,3) f32 -> out0 (B,3,S) f32
__global__ void k_out0(const float* __restrict__ NXYZ, float* __restrict__ out0) {
    int e = blockIdx.x * 256 + threadIdx.x;
    if (e >= BB * 3 * SS) return;
    int s = e % SS;
    int bc = e / SS;
    int c = bc % 3;
    int b = bc / 3;
    out0[e] = NXYZ[((size_t)b * SS + s) * 3 + c];
}

extern "C" void kernel_launch(void* const* d_in, const int* in_sizes, int n_in,
                              void* d_out, int out_size, void* d_ws, size_t ws_size,
                              hipStream_t stream) {
    const float* xyz = (const float*)d_in[0];
    const float* pts = (const float*)d_in[1];
    const float* w1q = (const float*)d_in[2];
    const float* w1k = (const float*)d_in[3];
    const float* w1v = (const float*)d_in[4];
    const float* w1o = (const float*)d_in[5];
    const float* w1p = (const float*)d_in[6];
    const float* b1p = (const float*)d_in[7];
    const float* w2q = (const float*)d_in[8];
    const float* w2k = (const float*)d_in[9];
    const float* w2v = (const float*)d_in[10];
    const float* w2o = (const float*)d_in[11];
    const float* w2p = (const float*)d_in[12];
    const float* b2p = (const float*)d_in[13];

    float* X = (float*)d_ws;                               // B*N*3
    float* NXYZ = X + (size_t)BB * NN * 3;                 // B*S*3
    int* GI = (int*)(NXYZ + (size_t)BB * SS * 3);          // B*S*32
    float* FMID = (float*)(GI + (size_t)BB * SS * 32);     // B*S*64
    float* Q2 = FMID + (size_t)BB * SS * 64;
    float* K2 = Q2 + (size_t)BB * SS * 64;
    float* V2 = K2 + (size_t)BB * SS * 64;

    float* out0 = (float*)d_out;
    float* out1 = out0 + (size_t)BB * 3 * SS;

    k_transpose<<<768, 256, 0, stream>>>(xyz, X);
    k_fps<<<BB, 1024, 0, stream>>>(X, NXYZ);
    k_ballq<<<4096, 256, 0, stream>>>(X, NXYZ, GI);
    k_attn1<<<16384, 256, 0, stream>>>(X, NXYZ, GI, pts, w1q, w1k, w1v, w1o,
                                       w1p, b1p, FMID);
    k_qkv2<<<4096, 256, 0, stream>>>(FMID, NXYZ, w2q, w2k, w2v, w2p, b2p,
                                     Q2, K2, V2);
    k_attn2<<<1024, 256, 0, stream>>>(Q2, K2, V2, FMID, w2o, out1);
    k_out0<<<192, 256, 0, stream>>>(NXYZ, out0);
}

// Round 19
// 4673.262 us; speedup vs baseline: 1.4022x; 1.4022x over previous
//
#include <hip/hip_runtime.h>
#include <hip/hip_bf16.h>
#include <math.h>

#define BB 8
#define NN 8192
#define SS 2048
#define NSAMP 32

typedef unsigned long long u64;

// K0: transpose xyz (B,3,N) f32 -> X (B,N,3) f32
__global__ void k_transpose(const float* __restrict__ xyz, float* __restrict__ X) {
    int e = blockIdx.x * 256 + threadIdx.x;
    if (e >= BB * 3 * NN) return;
    int n = e % NN;
    int bc = e / NN;
    int c = bc % 3;
    int b = bc / 3;
    X[((size_t)(b * NN + n)) * 3 + c] = xyz[e];
}

// K1: farthest point sampling, one block per batch.
// ARITHMETIC FROZEN (bit-exact vs reference, r18 PASS): direct distance,
// ascending, separately rounded (NO FMA); dists=fminf; argmax=first-max
// (smallest global index on ties).
// r19 perf change: 1024 -> 256 threads (4 waves = 4 SIMDs). The parallel
// distance update is thread-count-invariant in issue cycles, but 16 waves
// caused 4x issue contention and slow 16-wave barriers/scan on the 2048-step
// serial path. Mapping: thread tid holds points {tid + 256*i}, i=0..31 —
// in-thread first-max over ascending i = smallest n; cross-thread tie-break
// on smallest index preserved => argmax semantics identical.
__global__ __launch_bounds__(256) void k_fps(const float* __restrict__ X,
                                             float* __restrict__ NXYZ) {
    __shared__ float wv_[4];
    __shared__ int wn_[4];
    int b = blockIdx.x;
    int tid = threadIdx.x;
    const float* xb = X + (size_t)b * NN * 3;
    float px[32], py[32], pz[32], dist[32];
#pragma unroll
    for (int i = 0; i < 32; ++i) {
        int n = tid + (i << 8);
        px[i] = xb[(size_t)n * 3 + 0];
        py[i] = xb[(size_t)n * 3 + 1];
        pz[i] = xb[(size_t)n * 3 + 2];
        dist[i] = 1e10f;
    }
    float c0 = xb[0], c1 = xb[1], c2 = xb[2];
    int lane = tid & 63, wv = tid >> 6;
    for (int t = 0; t < SS; ++t) {
        if (tid == 0) {
            float* o = NXYZ + ((size_t)b * SS + t) * 3;
            o[0] = c0; o[1] = c1; o[2] = c2;
        }
        float bestv = -1.0f; int bestn = 0;
#pragma unroll
        for (int i = 0; i < 32; ++i) {
            float dx = __fsub_rn(px[i], c0);
            float dy = __fsub_rn(py[i], c1);
            float dz = __fsub_rn(pz[i], c2);
            float dd = __fadd_rn(__fadd_rn(__fmul_rn(dx, dx), __fmul_rn(dy, dy)),
                                 __fmul_rn(dz, dz));
            float nd = fminf(dist[i], dd);
            dist[i] = nd;
            if (nd > bestv) { bestv = nd; bestn = tid + (i << 8); }
        }
        // wave-level reduction: max value, ties -> smallest index
#pragma unroll
        for (int off = 32; off > 0; off >>= 1) {
            float ov = __shfl_down(bestv, (unsigned)off, 64);
            int on = __shfl_down(bestn, (unsigned)off, 64);
            if (ov > bestv || (ov == bestv && on < bestn)) { bestv = ov; bestn = on; }
        }
        if (lane == 0) { wv_[wv] = bestv; wn_[wv] = bestn; }
        __syncthreads();
        float kv = wv_[0]; int kn = wn_[0];
#pragma unroll
        for (int i = 1; i < 4; ++i) {
            float ov = wv_[i]; int on = wn_[i];
            if (ov > kv || (ov == kv && on < kn)) { kv = ov; kn = on; }
        }
        int cur = kn;
        c0 = xb[(size_t)cur * 3 + 0];
        c1 = xb[(size_t)cur * 3 + 1];
        c2 = xb[(size_t)cur * 3 + 2];
        __syncthreads();  // protect wv_/wn_ before next iteration's writes
    }
}

// K2: ball query. One wave per center. ARITHMETIC FROZEN (r18 PASS):
//   dot = fma(c2,x2, fma(c1,x1, fl(c0*x0)))   (BLAS k=3 asc-FMA)
//   t   = fl(-2*dot + B)   B = (x0^2+x1^2)+x2^2  (asc, no FMA)
//   sqr = fl(t + A)        A = (c0^2+c1^2)+c2^2  (asc, no FMA)
//   exclude sqr > 0.04f
__global__ __launch_bounds__(256) void k_ballq(const float* __restrict__ X,
                                               const float* __restrict__ NXYZ,
                                               int* __restrict__ GI) {
    int wv = threadIdx.x >> 6, lane = threadIdx.x & 63;
    int gs = blockIdx.x * 4 + wv;           // 0..16383
    int b = gs >> 11;
    const float* xb = X + (size_t)b * NN * 3;
    float c0 = NXYZ[(size_t)gs * 3 + 0];
    float c1 = NXYZ[(size_t)gs * 3 + 1];
    float c2 = NXYZ[(size_t)gs * 3 + 2];
    float A = __fadd_rn(__fadd_rn(__fmul_rn(c0, c0), __fmul_rn(c1, c1)),
                        __fmul_rn(c2, c2));
    const float R2 = 0.04f;
    int cnt = 0, first = 0;
    int* gout = GI + ((size_t)gs << 5);
    for (int r = 0; r < 128 && cnt < 32; ++r) {
        int n = (r << 6) + lane;
        float x0 = xb[(size_t)n * 3 + 0];
        float x1 = xb[(size_t)n * 3 + 1];
        float x2 = xb[(size_t)n * 3 + 2];
        float Bx = __fadd_rn(__fadd_rn(__fmul_rn(x0, x0), __fmul_rn(x1, x1)),
                             __fmul_rn(x2, x2));
        float dot = fmaf(c2, x2, fmaf(c1, x1, __fmul_rn(c0, x0)));  // BLAS asc-FMA
        float t = __fadd_rn(__fmul_rn(-2.0f, dot), Bx);             // += B first
        float sqr = __fadd_rn(t, A);                                // += A second
        bool pred = !(sqr > R2);
        u64 mask = __ballot(pred);
        int rank = cnt + __popcll(mask & ((1ull << lane) - 1ull));
        if (pred && rank < 32) gout[rank] = n;
        if (cnt == 0 && mask) first = (r << 6) + (__ffsll((long long)mask) - 1);
        cnt += __popcll(mask);
    }
    if (cnt < 32 && lane >= cnt && lane < 32) gout[lane] = first;
}

// K3: build group features in LDS + attention block 1 + maxpool. One block per
// (b,s) group: 32 tokens x 64 dims.
__global__ __launch_bounds__(256) void k_attn1(
    const float* __restrict__ X, const float* __restrict__ NXYZ,
    const int* __restrict__ GI, const float* __restrict__ P,
    const float* __restrict__ wq, const float* __restrict__ wk,
    const float* __restrict__ wv, const float* __restrict__ wo,
    const float* __restrict__ wp, const float* __restrict__ bp,
    float* __restrict__ FMID) {
    __shared__ float feat[32][65], qS[32][65], kS[32][65], vS[32][65];
    __shared__ float sc[32][33];
    __shared__ float pos[32][3];
    __shared__ int giS[32];
    __shared__ float ctr[3];
    int gs = blockIdx.x;
    int b = gs >> 11;
    int tid = threadIdx.x;
    if (tid < 32) giS[tid] = GI[((size_t)gs << 5) + tid];
    if (tid < 3) ctr[tid] = NXYZ[(size_t)gs * 3 + tid];
    __syncthreads();
    const float* xb = X + (size_t)b * NN * 3;
    const float* pb = P + (size_t)b * 61 * NN;
    int d = tid & 63, g4 = tid >> 6;
    for (int jj = 0; jj < 8; ++jj) {
        int j = g4 * 8 + jj;
        int idx = giS[j];
        float val;
        if (d < 3) {
            float xv = xb[(size_t)idx * 3 + d];
            pos[j][d] = xv;
            val = __fsub_rn(xv, ctr[d]);
        } else {
            val = pb[(size_t)(d - 3) * NN + idx];
        }
        feat[j][d] = val;
    }
    __syncthreads();
    float aq[8], ak[8], av[8];
#pragma unroll
    for (int i = 0; i < 8; ++i) { aq[i] = 0.f; ak[i] = 0.f; av[i] = 0.f; }
    for (int kk = 0; kk < 64; ++kk) {
        float wqv = wq[kk * 64 + d];
        float wkv = wk[kk * 64 + d];
        float wvv = wv[kk * 64 + d];
#pragma unroll
        for (int i = 0; i < 8; ++i) {
            float f = feat[g4 + 4 * i][kk];
            aq[i] = fmaf(f, wqv, aq[i]);
            ak[i] = fmaf(f, wkv, ak[i]);
            av[i] = fmaf(f, wvv, av[i]);
        }
    }
    {
        float wp0 = wp[d], wp1 = wp[64 + d], wp2 = wp[128 + d];
        float bpd = bp[d];
#pragma unroll
        for (int i = 0; i < 8; ++i) {
            int j = g4 + 4 * i;
            float pterm = fmaf(pos[j][2], wp2, fmaf(pos[j][1], wp1, pos[j][0] * wp0)) + bpd;
            av[i] += pterm;
            qS[j][d] = aq[i]; kS[j][d] = ak[i]; vS[j][d] = av[i];
        }
    }
    __syncthreads();
    for (int e = tid; e < 1024; e += 256) {
        int r = e >> 5, ci = e & 31;
        float acc = 0.f;
        for (int kk = 0; kk < 64; ++kk) acc = fmaf(qS[r][kk], kS[ci][kk], acc);
        sc[r][ci] = acc * 0.125f;
    }
    __syncthreads();
    if (tid < 32) {
        float m = -INFINITY;
        for (int i2 = 0; i2 < 32; ++i2) m = fmaxf(m, sc[tid][i2]);
        float sum = 0.f;
        for (int i2 = 0; i2 < 32; ++i2) {
            float e2 = expf(sc[tid][i2] - m);
            sc[tid][i2] = e2; sum += e2;
        }
        float inv = 1.0f / sum;
        for (int i2 = 0; i2 < 32; ++i2) sc[tid][i2] *= inv;
    }
    __syncthreads();
    // a @ v -> reuse qS as attention output
    for (int e = tid; e < 2048; e += 256) {
        int j = e >> 6, dd2 = e & 63;
        float acc = 0.f;
        for (int s2 = 0; s2 < 32; ++s2) acc = fmaf(sc[j][s2], vS[s2][dd2], acc);
        qS[j][dd2] = acc;
    }
    __syncthreads();
    float o[8];
#pragma unroll
    for (int i = 0; i < 8; ++i) o[i] = feat[g4 + 4 * i][d];
    for (int kk = 0; kk < 64; ++kk) {
        float wov = wo[kk * 64 + d];
#pragma unroll
        for (int i = 0; i < 8; ++i) o[i] = fmaf(qS[g4 + 4 * i][kk], wov, o[i]);
    }
    float pm = o[0];
#pragma unroll
    for (int i = 1; i < 8; ++i) pm = fmaxf(pm, o[i]);
    __syncthreads();
    feat[g4][d] = pm;
    __syncthreads();
    if (tid < 64) {
        float mm = fmaxf(fmaxf(feat[0][tid], feat[1][tid]),
                         fmaxf(feat[2][tid], feat[3][tid]));
        FMID[((size_t)gs << 6) + tid] = mm;
    }
}

// K4: q/k/v projections for attention block 2 (rows = B*2048)
__global__ __launch_bounds__(256) void k_qkv2(
    const float* __restrict__ FMID, const float* __restrict__ NXYZ,
    const float* __restrict__ wq, const float* __restrict__ wk,
    const float* __restrict__ wv, const float* __restrict__ wp,
    const float* __restrict__ bpv,
    float* __restrict__ Q2, float* __restrict__ K2, float* __restrict__ V2) {
    __shared__ float f[4][65];
    int tid = threadIdx.x;
    int lr = tid >> 6, d = tid & 63;
    size_t row = (size_t)blockIdx.x * 4 + lr;
    f[lr][d] = FMID[row * 64 + d];
    __syncthreads();
    float aq = 0.f, ak = 0.f, av = 0.f;
    for (int kk = 0; kk < 64; ++kk) {
        float fv = f[lr][kk];
        aq = fmaf(fv, wq[kk * 64 + d], aq);
        ak = fmaf(fv, wk[kk * 64 + d], ak);
        av = fmaf(fv, wv[kk * 64 + d], av);
    }
    float p0 = NXYZ[row * 3], p1 = NXYZ[row * 3 + 1], p2 = NXYZ[row * 3 + 2];
    av += fmaf(p2, wp[128 + d], fmaf(p1, wp[64 + d], p0 * wp[d])) + bpv[d];
    Q2[row * 64 + d] = aq; K2[row * 64 + d] = ak; V2[row * 64 + d] = av;
}

// K5: attention block 2, flash-style online softmax. 16 Q-rows per block
// (4 waves x 4 rows), K/V staged in padded LDS tiles of 64 rows.
__global__ __launch_bounds__(256) void k_attn2(
    const float* __restrict__ Q2, const float* __restrict__ K2,
    const float* __restrict__ V2, const float* __restrict__ FMID,
    const float* __restrict__ wo, float* __restrict__ out1) {
    __shared__ float kT[64][65], vT[64][65], qSh[16][65];
    int tid = threadIdx.x;
    int wv = tid >> 6, lane = tid & 63;
    int b = blockIdx.x >> 7, rb = blockIdx.x & 127;
    size_t rbase = (size_t)b * SS + rb * 16;
    for (int e = tid; e < 16 * 64; e += 256) {
        int r = e >> 6, dd = e & 63;
        qSh[r][dd] = Q2[(rbase + r) * 64 + dd];
    }
    float acc[4] = {0.f, 0.f, 0.f, 0.f};
    float mr[4] = {-INFINITY, -INFINITY, -INFINITY, -INFINITY};
    float lr[4] = {0.f, 0.f, 0.f, 0.f};
    for (int tt = 0; tt < 32; ++tt) {
        __syncthreads();
        for (int e = tid; e < 4096; e += 256) {
            int r = e >> 6, dd = e & 63;
            size_t src = ((size_t)b * SS + tt * 64 + r) * 64 + dd;
            kT[r][dd] = K2[src];
            vT[r][dd] = V2[src];
        }
        __syncthreads();
#pragma unroll
        for (int rr = 0; rr < 4; ++rr) {
            int lrow = wv * 4 + rr;
            float sj = 0.f;
            for (int dd = 0; dd < 64; ++dd) sj = fmaf(qSh[lrow][dd], kT[lane][dd], sj);
            sj *= 0.125f;
            float tm = sj;
#pragma unroll
            for (int off = 32; off > 0; off >>= 1)
                tm = fmaxf(tm, __shfl_down(tm, (unsigned)off, 64));
            tm = __shfl(tm, 0, 64);
            float mnew = fmaxf(mr[rr], tm);
            float alpha = expf(mr[rr] - mnew);
            float pj = expf(sj - mnew);
            float ps = pj;
#pragma unroll
            for (int off = 32; off > 0; off >>= 1) ps += __shfl_down(ps, (unsigned)off, 64);
            ps = __shfl(ps, 0, 64);
            lr[rr] = lr[rr] * alpha + ps;
            float a2 = acc[rr] * alpha;
            for (int j = 0; j < 64; ++j) {
                float pb2 = __shfl(pj, j, 64);
                a2 = fmaf(pb2, vT[j][lane], a2);
            }
            acc[rr] = a2;
            mr[rr] = mnew;
        }
    }
#pragma unroll
    for (int rr = 0; rr < 4; ++rr) {
        int lrow = wv * 4 + rr;
        size_t row = rbase + lrow;
        float avl = acc[rr] / lr[rr];
        float o = FMID[row * 64 + lane];
        for (int kk = 0; kk < 64; ++kk) {
            float avk = __shfl(avl, kk, 64);
            o = fmaf(avk, wo[kk * 64 + lane], o);
        }
        out1[((size_t)b * 64 + lane) * SS + (size_t)(rb * 16 + lrow)] = o;
    }
}

// K6: new_xyz (B,S,3) f32 -> out0 (B,3,S) f32
__global__ void k_out0(const float* __restrict__ NXYZ, float* __restrict__ out0) {
    int e = blockIdx.x * 256 + threadIdx.x;
    if (e >= BB * 3 * SS) return;
    int s = e % SS;
    int bc = e / SS;
    int c = bc % 3;
    int b = bc / 3;
    out0[e] = NXYZ[((size_t)b * SS + s) * 3 + c];
}

extern "C" void kernel_launch(void* const* d_in, const int* in_sizes, int n_in,
                              void* d_out, int out_size, void* d_ws, size_t ws_size,
                              hipStream_t stream) {
    const float* xyz = (const float*)d_in[0];
    const float* pts = (const float*)d_in[1];
    const float* w1q = (const float*)d_in[2];
    const float* w1k = (const float*)d_in[3];
    const float* w1v = (const float*)d_in[4];
    const float* w1o = (const float*)d_in[5];
    const float* w1p = (const float*)d_in[6];
    const float* b1p = (const float*)d_in[7];
    const float* w2q = (const float*)d_in[8];
    const float* w2k = (const float*)d_in[9];
    const float* w2v = (const float*)d_in[10];
    const float* w2o = (const float*)d_in[11];
    const float* w2p = (const float*)d_in[12];
    const float* b2p = (const float*)d_in[13];

    float* X = (float*)d_ws;                               // B*N*3
    float* NXYZ = X + (size_t)BB * NN * 3;                 // B*S*3
    int* GI = (int*)(NXYZ + (size_t)BB * SS * 3);          // B*S*32
    float* FMID = (float*)(GI + (size_t)BB * SS * 32);     // B*S*64
    float* Q2 = FMID + (size_t)BB * SS * 64;
    float* K2 = Q2 + (size_t)BB * SS * 64;
    float* V2 = K2 + (size_t)BB * SS * 64;

    float* out0 = (float*)d_out;
    float* out1 = out0 + (size_t)BB * 3 * SS;

    k_transpose<<<768, 256, 0, stream>>>(xyz, X);
    k_fps<<<BB, 256, 0, stream>>>(X, NXYZ);
    k_ballq<<<4096, 256, 0, stream>>>(X, NXYZ, GI);
    k_attn1<<<16384, 256, 0, stream>>>(X, NXYZ, GI, pts, w1q, w1k, w1v, w1o,
                                       w1p, b1p, FMID);
    k_qkv2<<<4096, 256, 0, stream>>>(FMID, NXYZ, w2q, w2k, w2v, w2p, b2p,
                                     Q2, K2, V2);
    k_attn2<<<1024, 256, 0, stream>>>(Q2, K2, V2, FMID, w2o, out1);
    k_out0<<<192, 256, 0, stream>>>(NXYZ, out0);
}